// Round 4
// baseline (15304.028 us; speedup 1.0000x reference)
//
#include <hip/hip_runtime.h>
#include <hip/hip_bf16.h>

typedef __attribute__((ext_vector_type(8))) short bf16x8;
typedef __attribute__((ext_vector_type(4))) float f32x4;

#define C2LE 2.8853900817779268f   // 2*log2(e)
#define LOG2E 1.4426950408889634f

static __device__ __forceinline__ float blo(unsigned q) { return __uint_as_float(q << 16); }
static __device__ __forceinline__ float bhi(unsigned q) { return __uint_as_float(q & 0xFFFF0000u); }
// r = 1/(1+2^arg) (arg pre-scaled by 2*log2e); tanh = 1 - 2r
static __device__ __forceinline__ float rterm(float arg) {
  return __builtin_amdgcn_rcpf(1.0f + __builtin_amdgcn_exp2f(arg));
}
static __device__ __forceinline__ float sigm(float x) {
  return __builtin_amdgcn_rcpf(1.0f + __builtin_amdgcn_exp2f(-x * LOG2E));
}
static __device__ __forceinline__ float tanhe(float x) {
  return fmaf(-2.0f, __builtin_amdgcn_rcpf(1.0f + __builtin_amdgcn_exp2f(x * C2LE)), 1.0f);
}
static __device__ __forceinline__ unsigned packhilo(float x) {
  __hip_bfloat16 h = __float2bfloat16(x);
  float r = x - __bfloat162float(h);
  __hip_bfloat16 l = __float2bfloat16(r);
  return (unsigned)__bfloat16_as_ushort(h) | ((unsigned)__bfloat16_as_ushort(l) << 16);
}

// ---------------- pack kernels ----------------
// whB[sl][nb][kb][lane][i]: B-frag for phase1. o = sl*32+nb*16+(l&15); k = kb*32+(l>>4)*8+i; q=k>>1
__global__ void k_pack_whB(const float* __restrict__ wue, __hip_bfloat16* __restrict__ wp) {
  for (int idx = blockIdx.x * blockDim.x + threadIdx.x; idx < (16 * 2 * 32 * 64 * 8);
       idx += gridDim.x * blockDim.x) {
    int i = idx & 7, l = (idx >> 3) & 63, kb = (idx >> 9) & 31, nb = (idx >> 14) & 1, sl = idx >> 15;
    int o = sl * 32 + nb * 16 + (l & 15);
    int q = (kb * 32 + (l >> 4) * 8 + i) >> 1;
    wp[idx] = __float2bfloat16(wue[o * 1024 + q]);
  }
}
// w3B[sl][nb][kb][lane][i]: B-frag for phase3. g = nb*256+sl*16+(l&15); k = kb*32+(l>>4)*8+i
__global__ void k_pack_w3B(const float* __restrict__ wih, const float* __restrict__ whh,
                           __hip_bfloat16* __restrict__ wp) {
  for (int idx = blockIdx.x * blockDim.x + threadIdx.x; idx < (16 * 4 * 24 * 64 * 8);
       idx += gridDim.x * blockDim.x) {
    int i = idx & 7, l = (idx >> 3) & 63;
    int kb = (idx >> 9) % 24, hi = (idx >> 9) / 24;
    int nb = hi & 3, sl = hi >> 2;
    int g = nb * 256 + sl * 16 + (l & 15);
    int k = kb * 32 + (l >> 4) * 8 + i;
    float v = (k < 256) ? wih[g * 128 + (k >> 1)] : whh[g * 256 + ((k - 256) >> 1)];
    wp[idx] = __float2bfloat16(v);
  }
}
__global__ void k_bsum(const float* __restrict__ bih, const float* __restrict__ bhh,
                       float* __restrict__ bs) {
  int idx = blockIdx.x * blockDim.x + threadIdx.x;
  if (idx < 1024) bs[idx] = bih[idx] + bhh[idx];
}
// WxT[s][o] = W_ue[o][512+s]
__global__ void k_wxt(const float* __restrict__ wue, float* __restrict__ wxt) {
  for (int idx = blockIdx.x * blockDim.x + threadIdx.x; idx < 512 * 512;
       idx += gridDim.x * blockDim.x) {
    int o = idx & 511, s = idx >> 9;
    wxt[idx] = wue[o * 1024 + 512 + s];
  }
}

// proj_x: px2[b][s4g][d][4] = bf16(C2LE * proj_x[b,d,s]) with s = s4g*4 + (0..3)
__global__ __launch_bounds__(512) void k_projx(const float* __restrict__ x,
                                               const float* __restrict__ wxt,
                                               __hip_bfloat16* __restrict__ px2) {
  __shared__ alignas(16) float xsT[32][512];
  const int b = blockIdx.x;
  const int tid = threadIdx.x;
  for (int dt = 0; dt < 4; ++dt) {
    __syncthreads();
    const float4* xr = (const float4*)(x + ((size_t)b << 16) + (size_t)tid * 128 + dt * 32);
#pragma unroll
    for (int q = 0; q < 8; ++q) {
      float4 vx = xr[q];
      xsT[q * 4 + 0][tid] = vx.x;
      xsT[q * 4 + 1][tid] = vx.y;
      xsT[q * 4 + 2][tid] = vx.z;
      xsT[q * 4 + 3][tid] = vx.w;
    }
    __syncthreads();
    const int o = tid;
    float acc[32];
#pragma unroll
    for (int dd = 0; dd < 32; ++dd) acc[dd] = 0.f;
    for (int s4 = 0; s4 < 128; ++s4) {
      float w0 = wxt[(s4 * 4 + 0) * 512 + o];
      float w1 = wxt[(s4 * 4 + 1) * 512 + o];
      float w2 = wxt[(s4 * 4 + 2) * 512 + o];
      float w3 = wxt[(s4 * 4 + 3) * 512 + o];
#pragma unroll
      for (int dd = 0; dd < 32; ++dd) {
        float4 xv = *(const float4*)&xsT[dd][s4 * 4];
        acc[dd] = fmaf(w0, xv.x, fmaf(w1, xv.y, fmaf(w2, xv.z, fmaf(w3, xv.w, acc[dd]))));
      }
    }
    for (int dd = 0; dd < 32; ++dd) {
      int d = dt * 32 + dd;
      px2[(((size_t)b * 128 + (o >> 2)) * 128 + d) * 4 + (o & 3)] =
          __float2bfloat16(acc[dd] * C2LE);
    }
  }
}

// ---------------- group barrier (16 blocks, same XCD by bg = blockIdx&15) ----
static __device__ __forceinline__ void group_barrier(unsigned* ctr, unsigned target) {
  __syncthreads();
  if (threadIdx.x == 0) {
    __threadfence();  // publish our stores (L2 writeback, agent scope)
    __hip_atomic_fetch_add(ctr, 1u, __ATOMIC_RELAXED, __HIP_MEMORY_SCOPE_AGENT);
    while (__hip_atomic_fetch_add(ctr, 0u, __ATOMIC_RELAXED, __HIP_MEMORY_SCOPE_AGENT) < target)
      __builtin_amdgcn_s_sleep(2);
    __threadfence();  // invalidate stale caches before consuming others' data
  }
  __syncthreads();
}

// ---------------- main persistent kernel: 256 blocks = 16 groups x 16 slices ----
__global__ __launch_bounds__(1024) void k_main(
    const __hip_bfloat16* __restrict__ px2, const __hip_bfloat16* __restrict__ whB,
    const __hip_bfloat16* __restrict__ w3B, const float* __restrict__ bsum,
    const float* __restrict__ x, const float* __restrict__ ve,
    unsigned* __restrict__ hG, float* __restrict__ Eg, unsigned* __restrict__ ctrs,
    float* __restrict__ out) {
  __shared__ uint2 px_l2[16384];           // 128KB  [b][s4][d] (8B: 4 s per d)
  __shared__ unsigned u_Au[2048];          // 8KB    u A-frags [qc=32][b=16] 16B entries
  __shared__ float PH_part[2][16][32];     // 4KB    [khalf][b][s]
  __shared__ float gates_part[2][64][16];  // 8KB    [khalf][g64][b]
  __shared__ float c_l[16][16];            // 1KB    [jj][b]
  __shared__ float v_l[32];
  __shared__ float bs_l[64];
  __shared__ float vss_sh;

  const int bg = blockIdx.x & 15;   // group (same XCD across its 16 blocks)
  const int sl = blockIdx.x >> 4;   // slice
  const int tid = threadIdx.x;
  const int lane = tid & 63;
  const int w = tid >> 6;

  // ---- prologue
  {
    const uint2* ps = (const uint2*)px2;
#pragma unroll
    for (int i = 0; i < 16; ++i) {
      int idx = i * 1024 + tid;
      int b = idx >> 10, s4 = (idx >> 7) & 7, d = idx & 127;
      px_l2[idx] = ps[((size_t)(bg * 16 + b) * 128 + sl * 8 + s4) * 128 + d];
    }
  }
  if (tid < 32) v_l[tid] = ve[sl * 32 + tid];
  if (tid < 64) {
    int ty = tid >> 4, jj = tid & 15;
    bs_l[tid] = bsum[ty * 256 + sl * 16 + jj];
  }
  if (tid < 256) c_l[tid >> 4][tid & 15] = 0.f;
  if (tid == 0) {
    float s = 0.f;
    for (int i = 0; i < 32; ++i) s += ve[sl * 32 + i];
    vss_sh = s;
  }
  __syncthreads();

  unsigned* ctrA = ctrs + bg * 64;
  unsigned* ctrB = ctrs + bg * 64 + 32;
  const float vss = vss_sh;

  for (int t = 0; t < 512; ++t) {
    const int par = t & 1;
    const bf16x8* hA = (const bf16x8*)hG + ((size_t)par * 16 + bg) * 2048;

    // ---- Phase 1 (waves 0-3): PH[16b,32s] = hs(hilo) x WhB  |  wave 15: zero E[1-par] slice
    if (w < 4) {
      int nb = w & 1, kh = w >> 1;
      int r16 = lane >> 4, c16 = lane & 15;
      f32x4 acc = {0.f, 0.f, 0.f, 0.f};
      const bf16x8* bp = (const bf16x8*)whB + (((size_t)sl * 2 + nb) * 32 + kh * 16) * 64 + lane;
      const bf16x8* ap = hA + (kh * 64 + r16) * 16 + c16;
#pragma unroll 4
      for (int kb = 0; kb < 16; ++kb)
        acc = __builtin_amdgcn_mfma_f32_16x16x32_bf16(ap[kb * 64], bp[kb * 64], acc, 0, 0, 0);
#pragma unroll
      for (int rr = 0; rr < 4; ++rr) PH_part[kh][r16 * 4 + rr][nb * 16 + c16] = acc[rr];
    } else if (w == 15) {
      float* ez = Eg + (((size_t)(1 - par) * 16 + bg) * 16 + sl) * 128;
      ez[lane] = 0.f;
      ez[64 + lane] = 0.f;
    }
    __syncthreads();

    // ---- Phase 2: E-partials over this block's 32 s; thread = (b = wave, d-pair)
    {
      int b = tid >> 6, dp = tid & 63;
      const uint2* prow = &px_l2[b * 1024];
      float R0 = 0.f, R1 = 0.f;
#pragma unroll
      for (int s4 = 0; s4 < 8; ++s4) {
        uint4 q = *(const uint4*)&prow[s4 * 128 + 2 * dp];
        float p0 = (PH_part[0][b][s4 * 4 + 0] + PH_part[1][b][s4 * 4 + 0]) * C2LE;
        float p1 = (PH_part[0][b][s4 * 4 + 1] + PH_part[1][b][s4 * 4 + 1]) * C2LE;
        float p2 = (PH_part[0][b][s4 * 4 + 2] + PH_part[1][b][s4 * 4 + 2]) * C2LE;
        float p3 = (PH_part[0][b][s4 * 4 + 3] + PH_part[1][b][s4 * 4 + 3]) * C2LE;
        float v0 = v_l[s4 * 4 + 0], v1 = v_l[s4 * 4 + 1];
        float v2 = v_l[s4 * 4 + 2], v3 = v_l[s4 * 4 + 3];
        R0 = fmaf(v0, rterm(p0 + blo(q.x)), R0);
        R0 = fmaf(v1, rterm(p1 + bhi(q.x)), R0);
        R0 = fmaf(v2, rterm(p2 + blo(q.y)), R0);
        R0 = fmaf(v3, rterm(p3 + bhi(q.y)), R0);
        R1 = fmaf(v0, rterm(p0 + blo(q.z)), R1);
        R1 = fmaf(v1, rterm(p1 + bhi(q.z)), R1);
        R1 = fmaf(v2, rterm(p2 + blo(q.w)), R1);
        R1 = fmaf(v3, rterm(p3 + bhi(q.w)), R1);
      }
      float* ea = Eg + (((size_t)par * 16 + bg) * 16 + b) * 128;
      atomicAdd(ea + 2 * dp, fmaf(-2.f, R0, vss));
      atomicAdd(ea + 2 * dp + 1, fmaf(-2.f, R1, vss));
    }
    group_barrier(ctrA, 16u * (t + 1));

    // ---- softmax + u A-frag build (redundant per block; cheap)
    {
      int b = tid >> 6, dp = tid & 63;
      const float* ea = Eg + (((size_t)par * 16 + bg) * 16 + b) * 128;
      float2 Ev = *(const float2*)(ea + 2 * dp);
      float e0 = __builtin_amdgcn_exp2f(Ev.x * LOG2E);
      float e1 = __builtin_amdgcn_exp2f(Ev.y * LOG2E);
      float z = e0 + e1;
#pragma unroll
      for (int m = 1; m < 64; m <<= 1) z += __shfl_xor(z, m);
      float zinv = __builtin_amdgcn_rcpf(z);
      const float* xp = x + ((size_t)(bg * 16 + b) * 512 + t) * 128;
      float2 xv = *(const float2*)(xp + 2 * dp);
      float u0 = xv.x * e0 * zinv, u1 = xv.y * e1 * zinv;
      int sbase = ((dp >> 1) * 16 + b) * 4 + 2 * (dp & 1);
      u_Au[sbase] = packhilo(u0);
      u_Au[sbase + 1] = packhilo(u1);
    }
    __syncthreads();

    // ---- Phase 3 (waves 0-7): gates[16b,64g] = [u|h](hilo) x W3B
    if (w < 8) {
      int nb = w & 3, kh = w >> 2;
      int r16 = lane >> 4, c16 = lane & 15;
      f32x4 acc = {0.f, 0.f, 0.f, 0.f};
      const bf16x8* bp = (const bf16x8*)w3B + (((size_t)sl * 4 + nb) * 24 + kh * 12) * 64 + lane;
      if (kh == 0) {
#pragma unroll 4
        for (int kb = 0; kb < 8; ++kb) {
          bf16x8 av = *(const bf16x8*)&u_Au[((kb * 4 + r16) * 16 + c16) * 4];
          acc = __builtin_amdgcn_mfma_f32_16x16x32_bf16(av, bp[kb * 64], acc, 0, 0, 0);
        }
#pragma unroll
        for (int kb = 8; kb < 12; ++kb)
          acc = __builtin_amdgcn_mfma_f32_16x16x32_bf16(hA[((kb - 8) * 4 + r16) * 16 + c16],
                                                        bp[kb * 64], acc, 0, 0, 0);
      } else {
#pragma unroll 4
        for (int kb = 12; kb < 24; ++kb)
          acc = __builtin_amdgcn_mfma_f32_16x16x32_bf16(hA[((kb - 8) * 4 + r16) * 16 + c16],
                                                        bp[(kb - 12) * 64], acc, 0, 0, 0);
      }
#pragma unroll
      for (int rr = 0; rr < 4; ++rr) gates_part[kh][nb * 16 + c16][r16 * 4 + rr] = acc[rr];
    }
    __syncthreads();

    // ---- Phase 4 (tid<256): LSTM pointwise for our 16 j x 16 b; write out + hG[1-par]
    if (tid < 256) {
      int b = tid & 15, jj = tid >> 4;
      float gi = gates_part[0][jj][b] + gates_part[1][jj][b] + bs_l[jj];
      float gf = gates_part[0][16 + jj][b] + gates_part[1][16 + jj][b] + bs_l[16 + jj];
      float gg = gates_part[0][32 + jj][b] + gates_part[1][32 + jj][b] + bs_l[32 + jj];
      float go = gates_part[0][48 + jj][b] + gates_part[1][48 + jj][b] + bs_l[48 + jj];
      float i_ = sigm(gi), f_ = sigm(gf), g_ = tanhe(gg), o_ = sigm(go);
      float c_new = fmaf(f_, c_l[jj][b], i_ * g_);
      float h_new = o_ * tanhe(c_new);
      c_l[jj][b] = c_new;
      __builtin_nontemporal_store(h_new,
                                  out + ((size_t)t * 256 + bg * 16 + b) * 256 + sl * 16 + jj);
      unsigned* hw = hG + (((size_t)(1 - par) * 16 + bg) * 2048 + (sl * 4 + (jj >> 2)) * 16 + b) * 4 +
                     (jj & 3);
      hw[0] = packhilo(h_new);
      hw[4096] = packhilo(c_new);  // c region: qc += 64 -> +64*16*4 uints
    }
    group_barrier(ctrB, 16u * (t + 1));
  }
}

// ---------------- host ----------------
extern "C" void kernel_launch(void* const* d_in, const int* in_sizes, int n_in,
                              void* d_out, int out_size, void* d_ws, size_t ws_size,
                              hipStream_t stream) {
  const float* x = (const float*)d_in[0];
  const float* wue = (const float*)d_in[1];
  const float* ve = (const float*)d_in[2];
  const float* wih = (const float*)d_in[3];
  const float* whh = (const float*)d_in[4];
  const float* bih = (const float*)d_in[5];
  const float* bhh = (const float*)d_in[6];
  float* out = (float*)d_out;

  char* ws = (char*)d_ws;
  __hip_bfloat16* px2 = (__hip_bfloat16*)(ws);              // 33,554,432 B
  __hip_bfloat16* whB = (__hip_bfloat16*)(ws + 33554432);   //  1,048,576 B
  __hip_bfloat16* w3B = (__hip_bfloat16*)(ws + 34603008);   //  1,572,864 B
  float* bsum = (float*)(ws + 36175872);                    //      4,096 B
  float* Eg = (float*)(ws + 36179968);                      //    262,144 B
  unsigned* ctrs = (unsigned*)(ws + 36442112);              //      4,096 B
  float* wxt = (float*)(ws + 36446208);                     //  1,048,576 B (overlaid w/ hG)
  unsigned* hG = (unsigned*)(ws + 36446208);                //  1,048,576 B

  k_pack_whB<<<1024, 256, 0, stream>>>(wue, whB);
  k_pack_w3B<<<1024, 256, 0, stream>>>(wih, whh, w3B);
  k_bsum<<<4, 256, 0, stream>>>(bih, bhh, bsum);
  k_wxt<<<256, 256, 0, stream>>>(wue, wxt);
  k_projx<<<256, 512, 0, stream>>>(x, wxt, px2);
  // barriers / E / h-state must start zeroed (wxt no longer needed -> hG overlay ok)
  hipMemsetAsync(hG, 0, 1048576, stream);
  hipMemsetAsync(Eg, 0, 262144, stream);
  hipMemsetAsync(ctrs, 0, 4096, stream);
  k_main<<<256, 1024, 0, stream>>>(px2, whB, w3B, bsum, x, ve, hG, Eg, ctrs, out);
}

// Round 5
// 6641.071 us; speedup vs baseline: 2.3045x; 2.3045x over previous
//
#include <hip/hip_runtime.h>
#include <hip/hip_bf16.h>

typedef __attribute__((ext_vector_type(8))) short bf16x8;
typedef __attribute__((ext_vector_type(4))) float f32x4;

#define C2LE 2.8853900817779268f   // 2*log2(e)
#define LOG2E 1.4426950408889634f

#define AGENT __HIP_MEMORY_SCOPE_AGENT
#define RLX __ATOMIC_RELAXED

static __device__ __forceinline__ float blo(unsigned q) { return __uint_as_float(q << 16); }
static __device__ __forceinline__ float bhi(unsigned q) { return __uint_as_float(q & 0xFFFF0000u); }
static __device__ __forceinline__ float rterm(float arg) {
  return __builtin_amdgcn_rcpf(1.0f + __builtin_amdgcn_exp2f(arg));
}
static __device__ __forceinline__ float sigm(float x) {
  return __builtin_amdgcn_rcpf(1.0f + __builtin_amdgcn_exp2f(-x * LOG2E));
}
static __device__ __forceinline__ float tanhe(float x) {
  return fmaf(-2.0f, __builtin_amdgcn_rcpf(1.0f + __builtin_amdgcn_exp2f(x * C2LE)), 1.0f);
}
static __device__ __forceinline__ unsigned packhilo(float x) {
  __hip_bfloat16 h = __float2bfloat16(x);
  float r = x - __bfloat162float(h);
  __hip_bfloat16 l = __float2bfloat16(r);
  return (unsigned)__bfloat16_as_ushort(h) | ((unsigned)__bfloat16_as_ushort(l) << 16);
}

// ---------------- pack kernels (identical to validated R4) ----------------
__global__ void k_pack_whB(const float* __restrict__ wue, __hip_bfloat16* __restrict__ wp) {
  for (int idx = blockIdx.x * blockDim.x + threadIdx.x; idx < (16 * 2 * 32 * 64 * 8);
       idx += gridDim.x * blockDim.x) {
    int i = idx & 7, l = (idx >> 3) & 63, kb = (idx >> 9) & 31, nb = (idx >> 14) & 1, sl = idx >> 15;
    int o = sl * 32 + nb * 16 + (l & 15);
    int q = (kb * 32 + (l >> 4) * 8 + i) >> 1;
    wp[idx] = __float2bfloat16(wue[o * 1024 + q]);
  }
}
__global__ void k_pack_w3B(const float* __restrict__ wih, const float* __restrict__ whh,
                           __hip_bfloat16* __restrict__ wp) {
  for (int idx = blockIdx.x * blockDim.x + threadIdx.x; idx < (16 * 4 * 24 * 64 * 8);
       idx += gridDim.x * blockDim.x) {
    int i = idx & 7, l = (idx >> 3) & 63;
    int kb = (idx >> 9) % 24, hi = (idx >> 9) / 24;
    int nb = hi & 3, sl = hi >> 2;
    int g = nb * 256 + sl * 16 + (l & 15);
    int k = kb * 32 + (l >> 4) * 8 + i;
    float v = (k < 256) ? wih[g * 128 + (k >> 1)] : whh[g * 256 + ((k - 256) >> 1)];
    wp[idx] = __float2bfloat16(v);
  }
}
__global__ void k_bsum(const float* __restrict__ bih, const float* __restrict__ bhh,
                       float* __restrict__ bs) {
  int idx = blockIdx.x * blockDim.x + threadIdx.x;
  if (idx < 1024) bs[idx] = bih[idx] + bhh[idx];
}
__global__ void k_wxt(const float* __restrict__ wue, float* __restrict__ wxt) {
  for (int idx = blockIdx.x * blockDim.x + threadIdx.x; idx < 512 * 512;
       idx += gridDim.x * blockDim.x) {
    int o = idx & 511, s = idx >> 9;
    wxt[idx] = wue[o * 1024 + 512 + s];
  }
}

__global__ __launch_bounds__(512) void k_projx(const float* __restrict__ x,
                                               const float* __restrict__ wxt,
                                               __hip_bfloat16* __restrict__ px2) {
  __shared__ alignas(16) float xsT[32][512];
  const int b = blockIdx.x;
  const int tid = threadIdx.x;
  for (int dt = 0; dt < 4; ++dt) {
    __syncthreads();
    const float4* xr = (const float4*)(x + ((size_t)b << 16) + (size_t)tid * 128 + dt * 32);
#pragma unroll
    for (int q = 0; q < 8; ++q) {
      float4 vx = xr[q];
      xsT[q * 4 + 0][tid] = vx.x;
      xsT[q * 4 + 1][tid] = vx.y;
      xsT[q * 4 + 2][tid] = vx.z;
      xsT[q * 4 + 3][tid] = vx.w;
    }
    __syncthreads();
    const int o = tid;
    float acc[32];
#pragma unroll
    for (int dd = 0; dd < 32; ++dd) acc[dd] = 0.f;
    for (int s4 = 0; s4 < 128; ++s4) {
      float w0 = wxt[(s4 * 4 + 0) * 512 + o];
      float w1 = wxt[(s4 * 4 + 1) * 512 + o];
      float w2 = wxt[(s4 * 4 + 2) * 512 + o];
      float w3 = wxt[(s4 * 4 + 3) * 512 + o];
#pragma unroll
      for (int dd = 0; dd < 32; ++dd) {
        float4 xv = *(const float4*)&xsT[dd][s4 * 4];
        acc[dd] = fmaf(w0, xv.x, fmaf(w1, xv.y, fmaf(w2, xv.z, fmaf(w3, xv.w, acc[dd]))));
      }
    }
    for (int dd = 0; dd < 32; ++dd) {
      int d = dt * 32 + dd;
      px2[(((size_t)b * 128 + (o >> 2)) * 128 + d) * 4 + (o & 3)] =
          __float2bfloat16(acc[dd] * C2LE);
    }
  }
}

// ---- fence-free group barrier: relaxed RMW + read-only polls.
// __syncthreads drains each wave's vmcnt, so all sc-flagged (atomic) data
// accesses are coherence-point-visible before the leader increments.
static __device__ __forceinline__ void gbar(unsigned* ctr, unsigned target) {
  __syncthreads();
  if (threadIdx.x == 0) {
    __hip_atomic_fetch_add(ctr, 1u, RLX, AGENT);
    while (__hip_atomic_load(ctr, RLX, AGENT) < target) __builtin_amdgcn_s_sleep(2);
  }
  __syncthreads();
}

// ---------------- main persistent kernel: 16 groups x 16 slices ----------------
__global__ __launch_bounds__(1024) void k_main(
    const __hip_bfloat16* __restrict__ px2, const __hip_bfloat16* __restrict__ whB,
    const __hip_bfloat16* __restrict__ w3B, const float* __restrict__ bsum,
    const float* __restrict__ x, const float* __restrict__ ve,
    unsigned* __restrict__ hG, float* __restrict__ Eg, unsigned* __restrict__ ctrs,
    float* __restrict__ out) {
  __shared__ alignas(16) bf16x8 hA_l[2048];  // 32KB staged h/c A-frags
  __shared__ unsigned u_Au[2048];            // 8KB u A-frags
  __shared__ float PH_part[2][16][32];
  __shared__ float gates_part[2][64][16];
  __shared__ float c_l[16][16];              // f32 carry state (exact)
  __shared__ float v_l[32];
  __shared__ float bs_l[64];
  __shared__ float vss_sh;

  const int bg = blockIdx.x & 15;
  const int sl = blockIdx.x >> 4;
  const int tid = threadIdx.x;
  const int lane = tid & 63;
  const int w = tid >> 6;

  // ---- prologue: px slice into REGISTERS (thread = (b=w, d-pair=lane))
  uint4 pxr[8];
  {
    const uint2* ps = (const uint2*)px2 + (((size_t)(bg * 16 + w) * 128 + sl * 8) * 128) + 2 * lane;
#pragma unroll
    for (int s4 = 0; s4 < 8; ++s4) pxr[s4] = *(const uint4*)(ps + (size_t)s4 * 128);
  }
  if (tid < 32) v_l[tid] = ve[sl * 32 + tid];
  if (tid < 64) bs_l[tid] = bsum[(tid >> 4) * 256 + sl * 16 + (tid & 15)];
  if (tid < 256) c_l[tid >> 4][tid & 15] = 0.f;
  if (tid == 0) {
    float s = 0.f;
    for (int i = 0; i < 32; ++i) s += ve[sl * 32 + i];
    vss_sh = s;
  }
  __syncthreads();

  unsigned* ctrA = ctrs + bg * 64;
  unsigned* ctrB = ctrs + bg * 64 + 32;
  const float vss = vss_sh;

  for (int t = 0; t < 512; ++t) {
    const int par = t & 1;

    // ---- stage h/c A-frags from coherence point into LDS (8B atomic loads)
    {
      const unsigned long long* hp =
          (const unsigned long long*)hG + ((size_t)par * 16 + bg) * 4096;
      unsigned long long* hl = (unsigned long long*)hA_l;
      unsigned long long v0 = __hip_atomic_load(hp + 2 * tid, RLX, AGENT);
      unsigned long long v1 = __hip_atomic_load(hp + 2 * tid + 1, RLX, AGENT);
      unsigned long long v2 = __hip_atomic_load(hp + 2 * tid + 2048, RLX, AGENT);
      unsigned long long v3 = __hip_atomic_load(hp + 2 * tid + 2049, RLX, AGENT);
      hl[2 * tid] = v0;
      hl[2 * tid + 1] = v1;
      hl[2 * tid + 2048] = v2;
      hl[2 * tid + 2049] = v3;
    }
    __syncthreads();

    // ---- Phase 1 (waves 0-3): PH = hs(hilo) x WhB  |  wave 15: zero next-par E slice
    if (w < 4) {
      int nb = w & 1, kh = w >> 1;
      int r16 = lane >> 4, c16 = lane & 15;
      f32x4 acc = {0.f, 0.f, 0.f, 0.f};
      const bf16x8* bp = (const bf16x8*)whB + (((size_t)sl * 2 + nb) * 32 + kh * 16) * 64 + lane;
      const bf16x8* ap = hA_l + (kh * 64 + r16) * 16 + c16;
#pragma unroll 4
      for (int kb = 0; kb < 16; ++kb)
        acc = __builtin_amdgcn_mfma_f32_16x16x32_bf16(ap[kb * 64], bp[kb * 64], acc, 0, 0, 0);
#pragma unroll
      for (int rr = 0; rr < 4; ++rr) PH_part[kh][r16 * 4 + rr][nb * 16 + c16] = acc[rr];
    } else if (w == 15) {
      float* ez = Eg + (((size_t)(1 - par) * 16 + bg) * 16 + sl) * 128;
      __hip_atomic_store(ez + lane, 0.f, RLX, AGENT);
      __hip_atomic_store(ez + 64 + lane, 0.f, RLX, AGENT);
    }
    __syncthreads();

    // ---- Phase 2: E-partials over our 32 s; thread = (b=w, d-pair=lane)
    {
      int b = w, dp = lane;
      float R0 = 0.f, R1 = 0.f;
#pragma unroll
      for (int s4 = 0; s4 < 8; ++s4) {
        uint4 q = pxr[s4];
        float p0 = (PH_part[0][b][s4 * 4 + 0] + PH_part[1][b][s4 * 4 + 0]) * C2LE;
        float p1 = (PH_part[0][b][s4 * 4 + 1] + PH_part[1][b][s4 * 4 + 1]) * C2LE;
        float p2 = (PH_part[0][b][s4 * 4 + 2] + PH_part[1][b][s4 * 4 + 2]) * C2LE;
        float p3 = (PH_part[0][b][s4 * 4 + 3] + PH_part[1][b][s4 * 4 + 3]) * C2LE;
        float v0 = v_l[s4 * 4 + 0], v1 = v_l[s4 * 4 + 1];
        float v2 = v_l[s4 * 4 + 2], v3 = v_l[s4 * 4 + 3];
        R0 = fmaf(v0, rterm(p0 + blo(q.x)), R0);
        R0 = fmaf(v1, rterm(p1 + bhi(q.x)), R0);
        R0 = fmaf(v2, rterm(p2 + blo(q.y)), R0);
        R0 = fmaf(v3, rterm(p3 + bhi(q.y)), R0);
        R1 = fmaf(v0, rterm(p0 + blo(q.z)), R1);
        R1 = fmaf(v1, rterm(p1 + bhi(q.z)), R1);
        R1 = fmaf(v2, rterm(p2 + blo(q.w)), R1);
        R1 = fmaf(v3, rterm(p3 + bhi(q.w)), R1);
      }
      float* ea = Eg + (((size_t)par * 16 + bg) * 16 + b) * 128;
      __hip_atomic_fetch_add(ea + 2 * dp, fmaf(-2.f, R0, vss), RLX, AGENT);
      __hip_atomic_fetch_add(ea + 2 * dp + 1, fmaf(-2.f, R1, vss), RLX, AGENT);
    }
    gbar(ctrA, 16u * (t + 1));

    // ---- softmax + u A-frag build (per-block redundant)
    {
      int b = w, dp = lane;
      const unsigned long long* ea =
          (const unsigned long long*)(Eg + (((size_t)par * 16 + bg) * 16 + b) * 128);
      unsigned long long ev = __hip_atomic_load(ea + dp, RLX, AGENT);
      float e0 = __builtin_amdgcn_exp2f(__uint_as_float((unsigned)ev) * LOG2E);
      float e1 = __builtin_amdgcn_exp2f(__uint_as_float((unsigned)(ev >> 32)) * LOG2E);
      float z = e0 + e1;
#pragma unroll
      for (int m = 1; m < 64; m <<= 1) z += __shfl_xor(z, m);
      float zinv = __builtin_amdgcn_rcpf(z);
      const float* xp = x + ((size_t)(bg * 16 + b) * 512 + t) * 128;
      float2 xv = *(const float2*)(xp + 2 * dp);
      float u0 = xv.x * e0 * zinv, u1 = xv.y * e1 * zinv;
      int sbase = ((dp >> 1) * 16 + b) * 4 + 2 * (dp & 1);
      u_Au[sbase] = packhilo(u0);
      u_Au[sbase + 1] = packhilo(u1);
    }
    __syncthreads();

    // ---- Phase 3 (waves 0-7): gates = [u|h](hilo) x W3B
    if (w < 8) {
      int nb = w & 3, kh = w >> 2;
      int r16 = lane >> 4, c16 = lane & 15;
      f32x4 acc = {0.f, 0.f, 0.f, 0.f};
      const bf16x8* bp = (const bf16x8*)w3B + (((size_t)sl * 4 + nb) * 24 + kh * 12) * 64 + lane;
      if (kh == 0) {
#pragma unroll 4
        for (int kb = 0; kb < 8; ++kb) {
          bf16x8 av = *(const bf16x8*)&u_Au[((kb * 4 + r16) * 16 + c16) * 4];
          acc = __builtin_amdgcn_mfma_f32_16x16x32_bf16(av, bp[kb * 64], acc, 0, 0, 0);
        }
#pragma unroll
        for (int kb = 8; kb < 12; ++kb)
          acc = __builtin_amdgcn_mfma_f32_16x16x32_bf16(hA_l[((kb - 8) * 4 + r16) * 16 + c16],
                                                        bp[kb * 64], acc, 0, 0, 0);
      } else {
#pragma unroll 4
        for (int kb = 12; kb < 24; ++kb)
          acc = __builtin_amdgcn_mfma_f32_16x16x32_bf16(hA_l[((kb - 8) * 4 + r16) * 16 + c16],
                                                        bp[(kb - 12) * 64], acc, 0, 0, 0);
      }
#pragma unroll
      for (int rr = 0; rr < 4; ++rr) gates_part[kh][nb * 16 + c16][r16 * 4 + rr] = acc[rr];
    }
    __syncthreads();

    // ---- Phase 4 (tid<256): LSTM pointwise; publish h/c hilo via sc-flagged stores
    if (tid < 256) {
      int b = tid & 15, jj = tid >> 4;
      float gi = gates_part[0][jj][b] + gates_part[1][jj][b] + bs_l[jj];
      float gf = gates_part[0][16 + jj][b] + gates_part[1][16 + jj][b] + bs_l[16 + jj];
      float gg = gates_part[0][32 + jj][b] + gates_part[1][32 + jj][b] + bs_l[32 + jj];
      float go = gates_part[0][48 + jj][b] + gates_part[1][48 + jj][b] + bs_l[48 + jj];
      float i_ = sigm(gi), f_ = sigm(gf), g_ = tanhe(gg), o_ = sigm(go);
      float c_new = fmaf(f_, c_l[jj][b], i_ * g_);
      float h_new = o_ * tanhe(c_new);
      c_l[jj][b] = c_new;
      __builtin_nontemporal_store(h_new,
                                  out + ((size_t)t * 256 + bg * 16 + b) * 256 + sl * 16 + jj);
      unsigned* hw = hG + ((size_t)(1 - par) * 16 + bg) * 8192 +
                     (((sl * 4 + (jj >> 2)) * 16 + b) * 4 + (jj & 3));
      __hip_atomic_store(hw, packhilo(h_new), RLX, AGENT);
      __hip_atomic_store(hw + 4096, packhilo(c_new), RLX, AGENT);
    }
    gbar(ctrB, 16u * (t + 1));
  }
}

// ---------------- host ----------------
extern "C" void kernel_launch(void* const* d_in, const int* in_sizes, int n_in,
                              void* d_out, int out_size, void* d_ws, size_t ws_size,
                              hipStream_t stream) {
  const float* x = (const float*)d_in[0];
  const float* wue = (const float*)d_in[1];
  const float* ve = (const float*)d_in[2];
  const float* wih = (const float*)d_in[3];
  const float* whh = (const float*)d_in[4];
  const float* bih = (const float*)d_in[5];
  const float* bhh = (const float*)d_in[6];
  float* out = (float*)d_out;

  char* ws = (char*)d_ws;
  __hip_bfloat16* px2 = (__hip_bfloat16*)(ws);              // 33,554,432 B
  __hip_bfloat16* whB = (__hip_bfloat16*)(ws + 33554432);   //  1,048,576 B
  __hip_bfloat16* w3B = (__hip_bfloat16*)(ws + 34603008);   //  1,572,864 B
  float* bsum = (float*)(ws + 36175872);                    //      4,096 B
  float* Eg = (float*)(ws + 36179968);                      //    262,144 B
  unsigned* ctrs = (unsigned*)(ws + 36442112);              //      4,096 B
  float* wxt = (float*)(ws + 36446208);                     //  1,048,576 B (overlaid w/ hG)
  unsigned* hG = (unsigned*)(ws + 36446208);                //  1,048,576 B

  k_pack_whB<<<1024, 256, 0, stream>>>(wue, whB);
  k_pack_w3B<<<1024, 256, 0, stream>>>(wih, whh, w3B);
  k_bsum<<<4, 256, 0, stream>>>(bih, bhh, bsum);
  k_wxt<<<256, 256, 0, stream>>>(wue, wxt);
  k_projx<<<256, 512, 0, stream>>>(x, wxt, px2);
  hipMemsetAsync(hG, 0, 1048576, stream);
  hipMemsetAsync(Eg, 0, 262144, stream);
  hipMemsetAsync(ctrs, 0, 4096, stream);
  k_main<<<256, 1024, 0, stream>>>(px2, whB, w3B, bsum, x, ve, hG, Eg, ctrs, out);
}

// Round 6
// 5126.718 us; speedup vs baseline: 2.9852x; 1.2954x over previous
//
#include <hip/hip_runtime.h>
#include <hip/hip_bf16.h>

typedef __attribute__((ext_vector_type(8))) short bf16x8;
typedef __attribute__((ext_vector_type(4))) float f32x4;

#define C2LE 2.8853900817779268f   // 2*log2(e)
#define LOG2E 1.4426950408889634f
#define AGENT __HIP_MEMORY_SCOPE_AGENT
#define RLX __ATOMIC_RELAXED

static __device__ __forceinline__ float blo(unsigned q) { return __uint_as_float(q << 16); }
static __device__ __forceinline__ float bhi(unsigned q) { return __uint_as_float(q & 0xFFFF0000u); }
static __device__ __forceinline__ float rterm(float arg) {
  return __builtin_amdgcn_rcpf(1.0f + __builtin_amdgcn_exp2f(arg));
}
static __device__ __forceinline__ float sigm(float x) {
  return __builtin_amdgcn_rcpf(1.0f + __builtin_amdgcn_exp2f(-x * LOG2E));
}
static __device__ __forceinline__ float tanhe(float x) {
  return fmaf(-2.0f, __builtin_amdgcn_rcpf(1.0f + __builtin_amdgcn_exp2f(x * C2LE)), 1.0f);
}
static __device__ __forceinline__ unsigned packhilo(float x) {
  __hip_bfloat16 h = __float2bfloat16(x);
  float r = x - __bfloat162float(h);
  __hip_bfloat16 l = __float2bfloat16(r);
  return (unsigned)__bfloat16_as_ushort(h) | ((unsigned)__bfloat16_as_ushort(l) << 16);
}
// paired uints (hi|lo<<16 per dim) -> hi/lo bf16x8 frags
static __device__ __forceinline__ void mkfrags(uint4 q0, uint4 q1, bf16x8& hi, bf16x8& lo) {
  uint4 h, l;
  h.x = __builtin_amdgcn_perm(q0.y, q0.x, 0x05040100u);
  h.y = __builtin_amdgcn_perm(q0.w, q0.z, 0x05040100u);
  h.z = __builtin_amdgcn_perm(q1.y, q1.x, 0x05040100u);
  h.w = __builtin_amdgcn_perm(q1.w, q1.z, 0x05040100u);
  l.x = __builtin_amdgcn_perm(q0.y, q0.x, 0x07060302u);
  l.y = __builtin_amdgcn_perm(q0.w, q0.z, 0x07060302u);
  l.z = __builtin_amdgcn_perm(q1.y, q1.x, 0x07060302u);
  l.w = __builtin_amdgcn_perm(q1.w, q1.z, 0x07060302u);
  hi = *(bf16x8*)&h;
  lo = *(bf16x8*)&l;
}

// ---------------- pack kernels ----------------
// whB[sl 8][nb 4][kap 16][l 64][j 8]: o = sl*64+nb*16+(l&15); dim = kap*32+(l>>4)*8+j
__global__ void k_pack_whB(const float* __restrict__ wue, __hip_bfloat16* __restrict__ wp) {
  for (int idx = blockIdx.x * blockDim.x + threadIdx.x; idx < 262144;
       idx += gridDim.x * blockDim.x) {
    int j = idx & 7, l = (idx >> 3) & 63, kap = (idx >> 9) & 15, nb = (idx >> 13) & 3,
        sl = idx >> 15;
    int o = sl * 64 + nb * 16 + (l & 15);
    int dim = kap * 32 + (l >> 4) * 8 + j;
    wp[idx] = __float2bfloat16(wue[o * 1024 + dim]);
  }
}
// w3B[sl 8][nb 8][ks 12][l 64][j 8]: n=nb*16+(l&15); g=(n>>5)*256+sl*32+(n&31); k=ks*32+(l>>4)*8+j
__global__ void k_pack_w3B(const float* __restrict__ wih, const float* __restrict__ whh,
                           __hip_bfloat16* __restrict__ wp) {
  for (int idx = blockIdx.x * blockDim.x + threadIdx.x; idx < 393216;
       idx += gridDim.x * blockDim.x) {
    int j = idx & 7, l = (idx >> 3) & 63;
    int ks = (idx >> 9) % 12, r = (idx >> 9) / 12;
    int nb = r & 7, sl = r >> 3;
    int n = nb * 16 + (l & 15);
    int g = (n >> 5) * 256 + sl * 32 + (n & 31);
    int k = ks * 32 + (l >> 4) * 8 + j;
    float v = (k < 128) ? wih[g * 128 + k] : whh[g * 256 + (k - 128)];
    wp[idx] = __float2bfloat16(v);
  }
}
__global__ void k_bsum(const float* __restrict__ bih, const float* __restrict__ bhh,
                       float* __restrict__ bs) {
  int idx = blockIdx.x * blockDim.x + threadIdx.x;
  if (idx < 1024) bs[idx] = bih[idx] + bhh[idx];
}
__global__ void k_wxt(const float* __restrict__ wue, float* __restrict__ wxt) {
  for (int idx = blockIdx.x * blockDim.x + threadIdx.x; idx < 512 * 512;
       idx += gridDim.x * blockDim.x) {
    int o = idx & 511, s = idx >> 9;
    wxt[idx] = wue[o * 1024 + 512 + s];
  }
}

// proj_x: px2[b][d][s] = bf16(C2LE * proj_x[b,d,s])
__global__ __launch_bounds__(512) void k_projx(const float* __restrict__ x,
                                               const float* __restrict__ wxt,
                                               __hip_bfloat16* __restrict__ px2) {
  __shared__ alignas(16) float xsT[32][512];
  const int b = blockIdx.x;
  const int tid = threadIdx.x;
  for (int dt = 0; dt < 4; ++dt) {
    __syncthreads();
    const float4* xr = (const float4*)(x + ((size_t)b << 16) + (size_t)tid * 128 + dt * 32);
#pragma unroll
    for (int q = 0; q < 8; ++q) {
      float4 vx = xr[q];
      xsT[q * 4 + 0][tid] = vx.x;
      xsT[q * 4 + 1][tid] = vx.y;
      xsT[q * 4 + 2][tid] = vx.z;
      xsT[q * 4 + 3][tid] = vx.w;
    }
    __syncthreads();
    const int o = tid;
    float acc[32];
#pragma unroll
    for (int dd = 0; dd < 32; ++dd) acc[dd] = 0.f;
    for (int s4 = 0; s4 < 128; ++s4) {
      float w0 = wxt[(s4 * 4 + 0) * 512 + o];
      float w1 = wxt[(s4 * 4 + 1) * 512 + o];
      float w2 = wxt[(s4 * 4 + 2) * 512 + o];
      float w3 = wxt[(s4 * 4 + 3) * 512 + o];
#pragma unroll
      for (int dd = 0; dd < 32; ++dd) {
        float4 xv = *(const float4*)&xsT[dd][s4 * 4];
        acc[dd] = fmaf(w0, xv.x, fmaf(w1, xv.y, fmaf(w2, xv.z, fmaf(w3, xv.w, acc[dd]))));
      }
    }
    for (int dd = 0; dd < 32; ++dd) {
      px2[((size_t)b * 128 + dt * 32 + dd) * 512 + o] = __float2bfloat16(acc[dd] * C2LE);
    }
  }
}

static __device__ __forceinline__ void gbar(unsigned* ctr, unsigned target) {
  __syncthreads();
  if (threadIdx.x == 0) {
    __hip_atomic_fetch_add(ctr, 1u, RLX, AGENT);
    while (__hip_atomic_load(ctr, RLX, AGENT) < target) __builtin_amdgcn_s_sleep(1);
  }
  __syncthreads();
}

// ---------------- main persistent kernel: 32 groups x 8 blocks ----------------
__global__ __launch_bounds__(1024) void k_main(
    const __hip_bfloat16* __restrict__ px2, const __hip_bfloat16* __restrict__ whB,
    const __hip_bfloat16* __restrict__ w3B, const float* __restrict__ bsum,
    const float* __restrict__ x, const float* __restrict__ ve,
    unsigned* __restrict__ hG, float* __restrict__ Eg, unsigned* __restrict__ ctrs,
    float* __restrict__ out) {
  __shared__ alignas(16) __hip_bfloat16 w3_l[49152];  // 96 KB W3 B-frags (unreplicated)
  __shared__ alignas(16) unsigned hA[8192];           // 32 KB paired h/c A-layout (16 ksteps)
  __shared__ alignas(16) unsigned uA[2048];           // 8 KB paired u A-layout (4 ksteps)
  __shared__ float PHp[4][8][64];                     // 8 KB
  __shared__ float PH[512];                           // 2 KB
  __shared__ float gp[2][128][8];                     // 8 KB
  __shared__ float c_l[32][8];                        // 1 KB
  __shared__ float v_l[64];
  __shared__ float bs_l[128];
  __shared__ float zpart[16];
  __shared__ float vss_sh;

  const int grp = blockIdx.x & 31;   // group: all 8 member blocks share blockIdx%32 -> same XCD
  const int sl = blockIdx.x >> 5;    // slice 0..7
  const int tid = threadIdx.x;
  const int lane = tid & 63;
  const int w = tid >> 6;
  const int b = tid >> 7;            // phase2/softmax thread mapping
  const int d = tid & 127;
  const int bG = grp * 8 + b;

  // ---- prologue: stage W3 slice to LDS, Wh frags + px to regs, zero hA/uA
  {
    const uint4* src = (const uint4*)(w3B + (size_t)sl * 49152);
    uint4* dst = (uint4*)w3_l;
    for (int i = tid; i < 6144; i += 1024) dst[i] = src[i];
  }
  bf16x8 whr[4];
  {
    const bf16x8* src =
        (const bf16x8*)whB + ((size_t)(sl * 4 + (w & 3)) * 16 + (w >> 2) * 4) * 64 + lane;
#pragma unroll
    for (int i = 0; i < 4; ++i) whr[i] = src[i * 64];
  }
  uint4 pxr[8];
  {
    const uint4* p4 = (const uint4*)(px2 + ((size_t)bG * 128 + d) * 512 + sl * 64);
#pragma unroll
    for (int i = 0; i < 8; ++i) pxr[i] = p4[i];
  }
  if (tid < 64) v_l[tid] = ve[sl * 64 + tid];
  if (tid < 128) bs_l[tid] = bsum[(tid >> 5) * 256 + sl * 32 + (tid & 31)];
  if (tid < 256) c_l[tid >> 3][tid & 7] = 0.f;
  for (int i = tid; i < 8192; i += 1024) hA[i] = 0;
  for (int i = tid; i < 2048; i += 1024) uA[i] = 0;
  if (tid == 0) {
    float s = 0.f;
    for (int i = 0; i < 64; ++i) s += ve[sl * 64 + i];
    vss_sh = s;
  }
  __syncthreads();
  const float vss = vss_sh;
  unsigned* ctrA = ctrs + grp * 64;
  unsigned* ctrB = ctrA + 32;

  for (int t = 0; t < 512; ++t) {
    const int par = t & 1;

    // ---- stage h/c (packed rows<8) from MALL into LDS A-layout
    {
      const unsigned long long* hp =
          (const unsigned long long*)(hG + (size_t)(par * 32 + grp) * 4096) + tid * 2;
      unsigned long long a0 = __hip_atomic_load(hp, RLX, AGENT);
      unsigned long long a1 = __hip_atomic_load(hp + 1, RLX, AGENT);
      int p = tid * 4;
      int jb = p & 7, bb = (p >> 3) & 7, rest = p >> 6;
      uint4 q;
      q.x = (unsigned)a0;
      q.y = (unsigned)(a0 >> 32);
      q.z = (unsigned)a1;
      q.w = (unsigned)(a1 >> 32);
      *(uint4*)&hA[rest * 128 + bb * 8 + jb] = q;
    }
    // zero next-par E slice (ours: 128 dwords)
    if (tid < 128)
      __hip_atomic_store(Eg + (size_t)((1 - par) * 32 + grp) * 1024 + sl * 128 + tid, 0.f, RLX,
                         AGENT);
    __syncthreads();

    // ---- Phase 1: PH[8b, 64o] = hs x Wh   (16 waves = 4nb x 4kq; hi+lo passes)
    {
      const int kq = w >> 2, nb = w & 3;
      f32x4 acc = {0.f, 0.f, 0.f, 0.f};
#pragma unroll
      for (int i = 0; i < 4; ++i) {
        const uint4* ap = (const uint4*)&hA[((kq * 4 + i) * 64 + lane) * 8];
        uint4 q0 = ap[0], q1 = ap[1];
        bf16x8 ahi, alo;
        mkfrags(q0, q1, ahi, alo);
        acc = __builtin_amdgcn_mfma_f32_16x16x32_bf16(ahi, whr[i], acc, 0, 0, 0);
        acc = __builtin_amdgcn_mfma_f32_16x16x32_bf16(alo, whr[i], acc, 0, 0, 0);
      }
      if (lane < 32) {
        int r16 = lane >> 4, c16 = lane & 15;
#pragma unroll
        for (int rr = 0; rr < 4; ++rr) PHp[kq][r16 * 4 + rr][nb * 16 + c16] = acc[rr];
      }
    }
    __syncthreads();
    if (tid < 512)
      PH[tid] = (PHp[0][tid >> 6][tid & 63] + PHp[1][tid >> 6][tid & 63] +
                 PHp[2][tid >> 6][tid & 63] + PHp[3][tid >> 6][tid & 63]) *
                C2LE;
    __syncthreads();

    // ---- Phase 2: E partial over our 64 s for (b, d); one atomicAdd each
    float xv = x[((size_t)bG * 512 + t) * 128 + d];  // prefetch (independent of E)
    {
      float R = 0.f;
      const float* PHb = &PH[b * 64];
#pragma unroll 2
      for (int s8 = 0; s8 < 8; ++s8) {
        uint4 q = pxr[s8];
        float4 pa = *(const float4*)&PHb[s8 * 8];
        float4 pb = *(const float4*)&PHb[s8 * 8 + 4];
        float4 va = *(const float4*)&v_l[s8 * 8];
        float4 vb = *(const float4*)&v_l[s8 * 8 + 4];
        R = fmaf(va.x, rterm(pa.x + blo(q.x)), R);
        R = fmaf(va.y, rterm(pa.y + bhi(q.x)), R);
        R = fmaf(va.z, rterm(pa.z + blo(q.y)), R);
        R = fmaf(va.w, rterm(pa.w + bhi(q.y)), R);
        R = fmaf(vb.x, rterm(pb.x + blo(q.z)), R);
        R = fmaf(vb.y, rterm(pb.y + bhi(q.z)), R);
        R = fmaf(vb.z, rterm(pb.z + blo(q.w)), R);
        R = fmaf(vb.w, rterm(pb.w + bhi(q.w)), R);
      }
      __hip_atomic_fetch_add(Eg + (size_t)(par * 32 + grp) * 1024 + b * 128 + d,
                             fmaf(-2.f, R, vss), RLX, AGENT);
    }
    gbar(ctrA, 8u * (t + 1));

    // ---- softmax + u A-frag build
    float Ev = __hip_atomic_load(Eg + (size_t)(par * 32 + grp) * 1024 + b * 128 + d, RLX, AGENT);
    float e = __builtin_amdgcn_exp2f(Ev * LOG2E);
    {
      float z = e;
#pragma unroll
      for (int m = 1; m < 64; m <<= 1) z += __shfl_xor(z, m);
      if (lane == 0) zpart[w] = z;
    }
    __syncthreads();
    {
      float zf = zpart[2 * b] + zpart[2 * b + 1];
      float u = xv * e * __builtin_amdgcn_rcpf(zf);
      uA[((d >> 5) * 64 + ((d >> 3) & 3) * 16 + b) * 8 + (d & 7)] = packhilo(u);
    }
    __syncthreads();

    // ---- Phase 3: gates[8b, 128n] = [u|h] x W3  (16 waves = 8nb x 2kh; hi+lo)
    {
      const int nb = w & 7, kh = w >> 3;
      f32x4 acc = {0.f, 0.f, 0.f, 0.f};
      const bf16x8* bp = (const bf16x8*)w3_l + ((size_t)nb * 12 + kh * 6) * 64 + lane;
#pragma unroll
      for (int i = 0; i < 6; ++i) {
        int ks = kh * 6 + i;
        const uint4* ap = (ks < 4) ? (const uint4*)&uA[(ks * 64 + lane) * 8]
                                   : (const uint4*)&hA[((ks - 4) * 64 + lane) * 8];
        uint4 q0 = ap[0], q1 = ap[1];
        bf16x8 ahi, alo;
        mkfrags(q0, q1, ahi, alo);
        bf16x8 bf = bp[i * 64];
        acc = __builtin_amdgcn_mfma_f32_16x16x32_bf16(ahi, bf, acc, 0, 0, 0);
        acc = __builtin_amdgcn_mfma_f32_16x16x32_bf16(alo, bf, acc, 0, 0, 0);
      }
      if (lane < 32) {
        int r16 = lane >> 4, c16 = lane & 15;
#pragma unroll
        for (int rr = 0; rr < 4; ++rr) gp[kh][nb * 16 + c16][r16 * 4 + rr] = acc[rr];
      }
    }
    __syncthreads();

    // ---- Phase 4: LSTM pointwise (8b x 32jj); publish h/c
    if (tid < 256) {
      int bb = tid & 7, jj = tid >> 3;
      float gi = gp[0][jj][bb] + gp[1][jj][bb] + bs_l[jj];
      float gf = gp[0][32 + jj][bb] + gp[1][32 + jj][bb] + bs_l[32 + jj];
      float gg = gp[0][64 + jj][bb] + gp[1][64 + jj][bb] + bs_l[64 + jj];
      float go = gp[0][96 + jj][bb] + gp[1][96 + jj][bb] + bs_l[96 + jj];
      float i_ = sigm(gi), f_ = sigm(gf), g_ = tanhe(gg), o_ = sigm(go);
      float c_new = fmaf(f_, c_l[jj][bb], i_ * g_);
      float h_new = o_ * tanhe(c_new);
      c_l[jj][bb] = c_new;
      __builtin_nontemporal_store(h_new,
                                  out + ((size_t)t * 256 + grp * 8 + bb) * 256 + sl * 32 + jj);
      int dd = sl * 32 + jj;
      int p = (((dd >> 5) * 4 + ((dd >> 3) & 3)) * 8 + bb) * 8 + (dd & 7);
      unsigned* hw = hG + (size_t)((1 - par) * 32 + grp) * 4096;
      __hip_atomic_store(hw + p, packhilo(h_new), RLX, AGENT);
      __hip_atomic_store(hw + p + 2048, packhilo(c_new), RLX, AGENT);
    }
    gbar(ctrB, 8u * (t + 1));
  }
}

// ---------------- host ----------------
extern "C" void kernel_launch(void* const* d_in, const int* in_sizes, int n_in,
                              void* d_out, int out_size, void* d_ws, size_t ws_size,
                              hipStream_t stream) {
  const float* x = (const float*)d_in[0];
  const float* wue = (const float*)d_in[1];
  const float* ve = (const float*)d_in[2];
  const float* wih = (const float*)d_in[3];
  const float* whh = (const float*)d_in[4];
  const float* bih = (const float*)d_in[5];
  const float* bhh = (const float*)d_in[6];
  float* out = (float*)d_out;

  char* ws = (char*)d_ws;
  __hip_bfloat16* px2 = (__hip_bfloat16*)(ws);             // 33,554,432 B
  __hip_bfloat16* whB = (__hip_bfloat16*)(ws + 33554432);  //    524,288 B
  __hip_bfloat16* w3B = (__hip_bfloat16*)(ws + 34078720);  //    786,432 B
  float* bsum = (float*)(ws + 34865152);                   //      4,096 B
  float* Eg = (float*)(ws + 34869248);                     //    262,144 B
  unsigned* ctrs = (unsigned*)(ws + 35131392);             //      8,192 B
  unsigned* hG = (unsigned*)(ws + 35139584);               //  1,048,576 B
  float* wxt = (float*)(ws + 36188160);                    //  1,048,576 B
  // total: 37,236,736 B

  k_pack_whB<<<1024, 256, 0, stream>>>(wue, whB);
  k_pack_w3B<<<1024, 256, 0, stream>>>(wih, whh, w3B);
  k_bsum<<<4, 256, 0, stream>>>(bih, bhh, bsum);
  k_wxt<<<256, 256, 0, stream>>>(wue, wxt);
  k_projx<<<256, 512, 0, stream>>>(x, wxt, px2);
  hipMemsetAsync(hG, 0, 1048576, stream);
  hipMemsetAsync(Eg, 0, 262144, stream);
  hipMemsetAsync(ctrs, 0, 8192, stream);
  k_main<<<256, 1024, 0, stream>>>(px2, whB, w3B, bsum, x, ve, hG, Eg, ctrs, out);
}

// Round 7
// 4916.409 us; speedup vs baseline: 3.1128x; 1.0428x over previous
//
#include <hip/hip_runtime.h>
#include <hip/hip_bf16.h>

typedef __attribute__((ext_vector_type(8))) short bf16x8;
typedef __attribute__((ext_vector_type(4))) float f32x4;

#define C2LE 2.8853900817779268f   // 2*log2(e)
#define LOG2E 1.4426950408889634f
#define AGENT __HIP_MEMORY_SCOPE_AGENT
#define RLX __ATOMIC_RELAXED

static __device__ __forceinline__ float blo(unsigned q) { return __uint_as_float(q << 16); }
static __device__ __forceinline__ float bhi(unsigned q) { return __uint_as_float(q & 0xFFFF0000u); }
static __device__ __forceinline__ float rterm(float arg) {
  return __builtin_amdgcn_rcpf(1.0f + __builtin_amdgcn_exp2f(arg));
}
static __device__ __forceinline__ float sigm(float x) {
  return __builtin_amdgcn_rcpf(1.0f + __builtin_amdgcn_exp2f(-x * LOG2E));
}
static __device__ __forceinline__ float tanhe(float x) {
  return fmaf(-2.0f, __builtin_amdgcn_rcpf(1.0f + __builtin_amdgcn_exp2f(x * C2LE)), 1.0f);
}
static __device__ __forceinline__ unsigned packhilo(float x) {
  __hip_bfloat16 h = __float2bfloat16(x);
  float r = x - __bfloat162float(h);
  __hip_bfloat16 l = __float2bfloat16(r);
  return (unsigned)__bfloat16_as_ushort(h) | ((unsigned)__bfloat16_as_ushort(l) << 16);
}
// paired uints (hi|lo<<16 per dim) -> hi/lo bf16x8 frags
static __device__ __forceinline__ void mkfrags(uint4 q0, uint4 q1, bf16x8& hi, bf16x8& lo) {
  uint4 h, l;
  h.x = __builtin_amdgcn_perm(q0.y, q0.x, 0x05040100u);
  h.y = __builtin_amdgcn_perm(q0.w, q0.z, 0x05040100u);
  h.z = __builtin_amdgcn_perm(q1.y, q1.x, 0x05040100u);
  h.w = __builtin_amdgcn_perm(q1.w, q1.z, 0x05040100u);
  l.x = __builtin_amdgcn_perm(q0.y, q0.x, 0x07060302u);
  l.y = __builtin_amdgcn_perm(q0.w, q0.z, 0x07060302u);
  l.z = __builtin_amdgcn_perm(q1.y, q1.x, 0x07060302u);
  l.w = __builtin_amdgcn_perm(q1.w, q1.z, 0x07060302u);
  hi = *(bf16x8*)&h;
  lo = *(bf16x8*)&l;
}
static __device__ __forceinline__ int swz(int e) { return e ^ ((e >> 4) & 7); }

// ---------------- pack kernels (unchanged, validated) ----------------
__global__ void k_pack_whB(const float* __restrict__ wue, __hip_bfloat16* __restrict__ wp) {
  for (int idx = blockIdx.x * blockDim.x + threadIdx.x; idx < 262144;
       idx += gridDim.x * blockDim.x) {
    int j = idx & 7, l = (idx >> 3) & 63, kap = (idx >> 9) & 15, nb = (idx >> 13) & 3,
        sl = idx >> 15;
    int o = sl * 64 + nb * 16 + (l & 15);
    int dim = kap * 32 + (l >> 4) * 8 + j;
    wp[idx] = __float2bfloat16(wue[o * 1024 + dim]);
  }
}
__global__ void k_pack_w3B(const float* __restrict__ wih, const float* __restrict__ whh,
                           __hip_bfloat16* __restrict__ wp) {
  for (int idx = blockIdx.x * blockDim.x + threadIdx.x; idx < 393216;
       idx += gridDim.x * blockDim.x) {
    int j = idx & 7, l = (idx >> 3) & 63;
    int ks = (idx >> 9) % 12, r = (idx >> 9) / 12;
    int nb = r & 7, sl = r >> 3;
    int n = nb * 16 + (l & 15);
    int g = (n >> 5) * 256 + sl * 32 + (n & 31);
    int k = ks * 32 + (l >> 4) * 8 + j;
    float v = (k < 128) ? wih[g * 128 + k] : whh[g * 256 + (k - 128)];
    wp[idx] = __float2bfloat16(v);
  }
}
__global__ void k_bsum(const float* __restrict__ bih, const float* __restrict__ bhh,
                       float* __restrict__ bs) {
  int idx = blockIdx.x * blockDim.x + threadIdx.x;
  if (idx < 1024) bs[idx] = bih[idx] + bhh[idx];
}
__global__ void k_wxt(const float* __restrict__ wue, float* __restrict__ wxt) {
  for (int idx = blockIdx.x * blockDim.x + threadIdx.x; idx < 512 * 512;
       idx += gridDim.x * blockDim.x) {
    int o = idx & 511, s = idx >> 9;
    wxt[idx] = wue[o * 1024 + 512 + s];
  }
}

__global__ __launch_bounds__(512) void k_projx(const float* __restrict__ x,
                                               const float* __restrict__ wxt,
                                               __hip_bfloat16* __restrict__ px2) {
  __shared__ alignas(16) float xsT[32][512];
  const int b = blockIdx.x;
  const int tid = threadIdx.x;
  for (int dt = 0; dt < 4; ++dt) {
    __syncthreads();
    const float4* xr = (const float4*)(x + ((size_t)b << 16) + (size_t)tid * 128 + dt * 32);
#pragma unroll
    for (int q = 0; q < 8; ++q) {
      float4 vx = xr[q];
      xsT[q * 4 + 0][tid] = vx.x;
      xsT[q * 4 + 1][tid] = vx.y;
      xsT[q * 4 + 2][tid] = vx.z;
      xsT[q * 4 + 3][tid] = vx.w;
    }
    __syncthreads();
    const int o = tid;
    float acc[32];
#pragma unroll
    for (int dd = 0; dd < 32; ++dd) acc[dd] = 0.f;
    for (int s4 = 0; s4 < 128; ++s4) {
      float w0 = wxt[(s4 * 4 + 0) * 512 + o];
      float w1 = wxt[(s4 * 4 + 1) * 512 + o];
      float w2 = wxt[(s4 * 4 + 2) * 512 + o];
      float w3 = wxt[(s4 * 4 + 3) * 512 + o];
#pragma unroll
      for (int dd = 0; dd < 32; ++dd) {
        float4 xv = *(const float4*)&xsT[dd][s4 * 4];
        acc[dd] = fmaf(w0, xv.x, fmaf(w1, xv.y, fmaf(w2, xv.z, fmaf(w3, xv.w, acc[dd]))));
      }
    }
    for (int dd = 0; dd < 32; ++dd) {
      px2[((size_t)b * 128 + dt * 32 + dd) * 512 + o] = __float2bfloat16(acc[dd] * C2LE);
    }
  }
}

// ---------------- main persistent kernel: 32 groups x 8 blocks ----------------
__global__ __launch_bounds__(1024) void k_main(
    const __hip_bfloat16* __restrict__ px2, const __hip_bfloat16* __restrict__ whB,
    const __hip_bfloat16* __restrict__ w3B, const float* __restrict__ bsum,
    const float* __restrict__ x, const float* __restrict__ ve,
    unsigned* __restrict__ hG, float* __restrict__ Eg, unsigned* __restrict__ ctrs,
    float* __restrict__ out) {
  __shared__ alignas(16) __hip_bfloat16 w3_l[49152];  // 96 KB W3 B-frags
  __shared__ alignas(16) uint4 hA0[1024];             // 16 KB (q0 halves, swizzled)
  __shared__ alignas(16) uint4 hA1[1024];             // 16 KB (q1 halves)
  __shared__ alignas(16) uint4 uA0[256];              // 4 KB
  __shared__ alignas(16) uint4 uA1[256];              // 4 KB
  __shared__ float PHp[4][8][64];                     // 8 KB
  __shared__ float PH[512];                           // 2 KB
  __shared__ float gp[2][128][9];                     // 9 KB (padded stride)
  __shared__ float c_l[32][8];                        // 1 KB
  __shared__ float v_l[64];
  __shared__ float bs_l[128];
  __shared__ float zpart[16];
  __shared__ float vss_sh;

  const int grp = blockIdx.x & 31;  // 8 member blocks share blockIdx%32 -> same XCD
  const int sl = blockIdx.x >> 5;   // slice 0..7
  const int tid = threadIdx.x;
  const int lane = tid & 63;
  const int w = tid >> 6;
  const int b = tid >> 7;  // phase2/softmax mapping
  const int d = tid & 127;
  const int bG = grp * 8 + b;

  // ---- prologue
  {
    const uint4* src = (const uint4*)(w3B + (size_t)sl * 49152);
    uint4* dst = (uint4*)w3_l;
    for (int i = tid; i < 6144; i += 1024) dst[i] = src[i];
  }
  bf16x8 whr[4];
  {
    const bf16x8* src =
        (const bf16x8*)whB + ((size_t)(sl * 4 + (w & 3)) * 16 + (w >> 2) * 4) * 64 + lane;
#pragma unroll
    for (int i = 0; i < 4; ++i) whr[i] = src[i * 64];
  }
  uint4 pxr[8];
  {
    const uint4* p4 = (const uint4*)(px2 + ((size_t)bG * 128 + d) * 512 + sl * 64);
#pragma unroll
    for (int i = 0; i < 8; ++i) pxr[i] = p4[i];
  }
  if (tid < 64) v_l[tid] = ve[sl * 64 + tid];
  if (tid < 128) bs_l[tid] = bsum[(tid >> 5) * 256 + sl * 32 + (tid & 31)];
  if (tid < 256) c_l[tid >> 3][tid & 7] = 0.f;
  {
    uint4 z = {0, 0, 0, 0};
    hA0[tid] = z;
    hA1[tid] = z;
    if (tid < 256) {
      uA0[tid] = z;
      uA1[tid] = z;
    }
  }
  if (tid == 0) {
    float s = 0.f;
    for (int i = 0; i < 64; ++i) s += ve[sl * 64 + i];
    vss_sh = s;
  }
  __syncthreads();
  const float vss = vss_sh;
  unsigned* ctrA = ctrs + grp * 64;
  unsigned* ctrB = ctrA + 32;
  float xv = x[((size_t)bG * 512) * 128 + d];  // x for t=0

  for (int t = 0; t < 512; ++t) {
    const int par = t & 1;

    // ---- stage h/c (compact) from coherence point into swizzled split LDS arrays
    {
      const unsigned long long* hp =
          (const unsigned long long*)(hG + (size_t)(par * 32 + grp) * 4096) + tid * 2;
      unsigned long long a0 = __hip_atomic_load(hp, RLX, AGENT);
      unsigned long long a1 = __hip_atomic_load(hp + 1, RLX, AGENT);
      int p = tid * 4;
      int e = ((p >> 6) << 4) + ((p >> 3) & 7);
      int ep = swz(e);
      uint4 q;
      q.x = (unsigned)a0;
      q.y = (unsigned)(a0 >> 32);
      q.z = (unsigned)a1;
      q.w = (unsigned)(a1 >> 32);
      if (p & 4) hA1[ep] = q;
      else hA0[ep] = q;
    }
    // zero next-par E slice (ours: 128 dwords)
    if (tid < 128)
      __hip_atomic_store(Eg + (size_t)((1 - par) * 32 + grp) * 1024 + sl * 128 + tid, 0.f, RLX,
                         AGENT);
    __syncthreads();

    // ---- Phase 1: PH[8b, 64o] = hs x Wh (16 waves = 4nb x 4kq; hi+lo passes)
    {
      const int kq = w >> 2, nb = w & 3;
      f32x4 acc = {0.f, 0.f, 0.f, 0.f};
#pragma unroll
      for (int i = 0; i < 4; ++i) {
        int ep = swz((kq * 4 + i) * 64 + lane);
        uint4 q0 = hA0[ep], q1 = hA1[ep];
        bf16x8 ahi, alo;
        mkfrags(q0, q1, ahi, alo);
        acc = __builtin_amdgcn_mfma_f32_16x16x32_bf16(ahi, whr[i], acc, 0, 0, 0);
        acc = __builtin_amdgcn_mfma_f32_16x16x32_bf16(alo, whr[i], acc, 0, 0, 0);
      }
      if (lane < 32) {
        int r16 = lane >> 4, c16 = lane & 15;
#pragma unroll
        for (int rr = 0; rr < 4; ++rr) PHp[kq][r16 * 4 + rr][nb * 16 + c16] = acc[rr];
      }
    }
    __syncthreads();
    if (tid < 512)
      PH[tid] = (PHp[0][tid >> 6][tid & 63] + PHp[1][tid >> 6][tid & 63] +
                 PHp[2][tid >> 6][tid & 63] + PHp[3][tid >> 6][tid & 63]) *
                C2LE;
    __syncthreads();

    // ---- Phase 2: E partial over our 64 s for (b,d); one atomicAdd
    {
      float R = 0.f;
      const float* PHb = &PH[b * 64];
#pragma unroll 2
      for (int s8 = 0; s8 < 8; ++s8) {
        uint4 q = pxr[s8];
        float4 pa = *(const float4*)&PHb[s8 * 8];
        float4 pb = *(const float4*)&PHb[s8 * 8 + 4];
        float4 va = *(const float4*)&v_l[s8 * 8];
        float4 vb = *(const float4*)&v_l[s8 * 8 + 4];
        R = fmaf(va.x, rterm(pa.x + blo(q.x)), R);
        R = fmaf(va.y, rterm(pa.y + bhi(q.x)), R);
        R = fmaf(va.z, rterm(pa.z + blo(q.y)), R);
        R = fmaf(va.w, rterm(pa.w + bhi(q.y)), R);
        R = fmaf(vb.x, rterm(pb.x + blo(q.z)), R);
        R = fmaf(vb.y, rterm(pb.y + bhi(q.z)), R);
        R = fmaf(vb.z, rterm(pb.z + blo(q.w)), R);
        R = fmaf(vb.w, rterm(pb.w + bhi(q.w)), R);
      }
      __hip_atomic_fetch_add(Eg + (size_t)(par * 32 + grp) * 1024 + b * 128 + d,
                             fmaf(-2.f, R, vss), RLX, AGENT);
    }

    // ---- Phase 3h (h-part of gates; independent of softmax) hides barrier A
    const int nb3 = w & 7, kh3 = w >> 3;
    f32x4 acc3 = {0.f, 0.f, 0.f, 0.f};
#pragma unroll
    for (int i = 0; i < 4; ++i) {
      int ks = 4 + kh3 * 4 + i;  // h ksteps 4..11 -> hA entries 0..7
      int ep = swz((ks - 4) * 64 + lane);
      uint4 q0 = hA0[ep], q1 = hA1[ep];
      bf16x8 ahi, alo;
      mkfrags(q0, q1, ahi, alo);
      bf16x8 bf = ((const bf16x8*)w3_l)[((size_t)nb3 * 12 + ks) * 64 + lane];
      acc3 = __builtin_amdgcn_mfma_f32_16x16x32_bf16(ahi, bf, acc3, 0, 0, 0);
      acc3 = __builtin_amdgcn_mfma_f32_16x16x32_bf16(alo, bf, acc3, 0, 0, 0);
    }
    // ---- barrier A (arrive after syncthreads drains E-adds; poll exposed only past 3h)
    __syncthreads();
    if (tid == 0) {
      __hip_atomic_fetch_add(ctrA, 1u, RLX, AGENT);
      while (__hip_atomic_load(ctrA, RLX, AGENT) < 8u * (t + 1)) __builtin_amdgcn_s_sleep(1);
    }
    __syncthreads();

    // ---- softmax + u A-frag build
    float Ev = __hip_atomic_load(Eg + (size_t)(par * 32 + grp) * 1024 + b * 128 + d, RLX, AGENT);
    float e = __builtin_amdgcn_exp2f(Ev * LOG2E);
    {
      float z = e;
#pragma unroll
      for (int m = 1; m < 64; m <<= 1) z += __shfl_xor(z, m);
      if (lane == 0) zpart[w] = z;
    }
    __syncthreads();
    {
      float zf = zpart[2 * b] + zpart[2 * b + 1];
      float u = xv * e * __builtin_amdgcn_rcpf(zf);
      int ep = swz((d >> 5) * 64 + ((d >> 3) & 3) * 16 + b);
      unsigned* dst = (d & 4) ? (unsigned*)&uA1[ep] : (unsigned*)&uA0[ep];
      dst[d & 3] = packhilo(u);
    }
    __syncthreads();

    // ---- Phase 3u: u-part of gates (ks 0..3)
#pragma unroll
    for (int i = 0; i < 2; ++i) {
      int ks = kh3 * 2 + i;
      int ep = swz(ks * 64 + lane);
      uint4 q0 = uA0[ep], q1 = uA1[ep];
      bf16x8 ahi, alo;
      mkfrags(q0, q1, ahi, alo);
      bf16x8 bf = ((const bf16x8*)w3_l)[((size_t)nb3 * 12 + ks) * 64 + lane];
      acc3 = __builtin_amdgcn_mfma_f32_16x16x32_bf16(ahi, bf, acc3, 0, 0, 0);
      acc3 = __builtin_amdgcn_mfma_f32_16x16x32_bf16(alo, bf, acc3, 0, 0, 0);
    }
    if (lane < 32) {
      int r16 = lane >> 4, c16 = lane & 15;
#pragma unroll
      for (int rr = 0; rr < 4; ++rr) gp[kh3][nb3 * 16 + c16][r16 * 4 + rr] = acc3[rr];
    }
    __syncthreads();

    // ---- Phase 4: LSTM pointwise (8b x 32jj); publish h/c
    float h_new;
    if (tid < 256) {
      int bb = tid & 7, jj = tid >> 3;
      float gi = gp[0][jj][bb] + gp[1][jj][bb] + bs_l[jj];
      float gf = gp[0][32 + jj][bb] + gp[1][32 + jj][bb] + bs_l[32 + jj];
      float gg = gp[0][64 + jj][bb] + gp[1][64 + jj][bb] + bs_l[64 + jj];
      float go = gp[0][96 + jj][bb] + gp[1][96 + jj][bb] + bs_l[96 + jj];
      float i_ = sigm(gi), f_ = sigm(gf), g_ = tanhe(gg), o_ = sigm(go);
      float c_new = fmaf(f_, c_l[jj][bb], i_ * g_);
      h_new = o_ * tanhe(c_new);
      c_l[jj][bb] = c_new;
      int dd = sl * 32 + jj;
      int p = (((dd >> 5) * 4 + ((dd >> 3) & 3)) * 8 + bb) * 8 + (dd & 7);
      unsigned* hw = hG + (size_t)((1 - par) * 32 + grp) * 4096;
      __hip_atomic_store(hw + p, packhilo(h_new), RLX, AGENT);
      __hip_atomic_store(hw + p + 2048, packhilo(c_new), RLX, AGENT);
    }
    // ---- barrier B; fill the poll window with out-store + next-x prefetch
    __syncthreads();
    if (tid == 0) __hip_atomic_fetch_add(ctrB, 1u, RLX, AGENT);
    if (tid < 256) {
      int bb = tid & 7, jj = tid >> 3;
      __builtin_nontemporal_store(h_new,
                                  out + ((size_t)t * 256 + grp * 8 + bb) * 256 + sl * 32 + jj);
    }
    int tn = (t < 511) ? t + 1 : 511;
    float xv_n = x[((size_t)bG * 512 + tn) * 128 + d];
    if (tid == 0) {
      while (__hip_atomic_load(ctrB, RLX, AGENT) < 8u * (t + 1)) __builtin_amdgcn_s_sleep(1);
    }
    __syncthreads();
    xv = xv_n;
  }
}

// ---------------- host ----------------
extern "C" void kernel_launch(void* const* d_in, const int* in_sizes, int n_in,
                              void* d_out, int out_size, void* d_ws, size_t ws_size,
                              hipStream_t stream) {
  const float* x = (const float*)d_in[0];
  const float* wue = (const float*)d_in[1];
  const float* ve = (const float*)d_in[2];
  const float* wih = (const float*)d_in[3];
  const float* whh = (const float*)d_in[4];
  const float* bih = (const float*)d_in[5];
  const float* bhh = (const float*)d_in[6];
  float* out = (float*)d_out;

  char* ws = (char*)d_ws;
  __hip_bfloat16* px2 = (__hip_bfloat16*)(ws);             // 33,554,432 B
  __hip_bfloat16* whB = (__hip_bfloat16*)(ws + 33554432);  //    524,288 B
  __hip_bfloat16* w3B = (__hip_bfloat16*)(ws + 34078720);  //    786,432 B
  float* bsum = (float*)(ws + 34865152);                   //      4,096 B
  float* Eg = (float*)(ws + 34869248);                     //    262,144 B
  unsigned* ctrs = (unsigned*)(ws + 35131392);             //      8,192 B
  unsigned* hG = (unsigned*)(ws + 35139584);               //  1,048,576 B
  float* wxt = (float*)(ws + 36188160);                    //  1,048,576 B
  // total: 37,236,736 B

  k_pack_whB<<<1024, 256, 0, stream>>>(wue, whB);
  k_pack_w3B<<<1024, 256, 0, stream>>>(wih, whh, w3B);
  k_bsum<<<4, 256, 0, stream>>>(bih, bhh, bsum);
  k_wxt<<<256, 256, 0, stream>>>(wue, wxt);
  k_projx<<<256, 512, 0, stream>>>(x, wxt, px2);
  hipMemsetAsync(hG, 0, 1048576, stream);
  hipMemsetAsync(Eg, 0, 262144, stream);
  hipMemsetAsync(ctrs, 0, 8192, stream);
  k_main<<<256, 1024, 0, stream>>>(px2, whB, w3B, bsum, x, ve, hG, Eg, ctrs, out);
}